// Round 1
// baseline (235.800 us; speedup 1.0000x reference)
//
#include <hip/hip_runtime.h>
#include <hip/hip_bf16.h>
#include <hip/hip_fp16.h>

#define B_ 4
#define N_ 8192
#define D_ 4096
#define E_ 64
#define M_ (B_ * N_)          // 32768 tokens total
#define BM 64
#define BK 64
#define NKCHUNK (D_ / BK)     // 64

typedef _Float16 half8 __attribute__((ext_vector_type(8)));
typedef float f32x4 __attribute__((ext_vector_type(4)));

union H4 { _Float16 h[4]; uint2 u2; };

// ---------------------------------------------------------------------------
// GEMM: gates = x @ w^T  (f16 MFMA, fp32 accumulate)
// epilogue: t0 = log(max(gate,1e-6)) -> t0buf ; S1[b][e] += sum_n max(gate,1e-6)
// ---------------------------------------------------------------------------
__global__ __launch_bounds__(256) void gemm_log(const float* __restrict__ x,
                                                const float* __restrict__ w,
                                                float* __restrict__ t0,
                                                float* __restrict__ S1) {
  // swizzled LDS: row stride 64 halves (128B); 16B unit index ^= (row & 7)
  __shared__ _Float16 As[BM * BK];
  __shared__ _Float16 Bs[E_ * BK];
  __shared__ float wsum[4][32];

  const int tid = threadIdx.x;
  const int lane = tid & 63;
  const int wv = tid >> 6;                 // wave 0..3
  const int rowBase = blockIdx.x * BM;     // global token row of tile
  const int b = rowBase / N_;              // batch (tiles never cross batches)

  const int sr = tid >> 4;                 // staging row 0..15
  const int sc4 = tid & 15;                // staging float4 col 0..15

  f32x4 acc[2][2] = {};
  float4 ar[4], br[4];

  // prologue: load K-chunk 0 into registers
#pragma unroll
  for (int i = 0; i < 4; ++i) {
    ar[i] = *(const float4*)&x[(size_t)(rowBase + sr + i * 16) * D_ + sc4 * 4];
    br[i] = *(const float4*)&w[(size_t)(sr + i * 16) * D_ + sc4 * 4];
  }

  const int wm = (wv >> 1) * 32;
  const int wn = (wv & 1) * 32;
  const int l15 = lane & 15;
  const int lq = lane >> 4;                // k-quarter 0..3

  for (int kc = 0; kc < NKCHUNK; ++kc) {
    __syncthreads();                       // previous compute done with LDS
    // convert fp32->f16, write swizzled
#pragma unroll
    for (int i = 0; i < 4; ++i) {
      const int r = sr + i * 16;
      H4 ha, hb;
      ha.h[0] = (_Float16)ar[i].x; ha.h[1] = (_Float16)ar[i].y;
      ha.h[2] = (_Float16)ar[i].z; ha.h[3] = (_Float16)ar[i].w;
      hb.h[0] = (_Float16)br[i].x; hb.h[1] = (_Float16)br[i].y;
      hb.h[2] = (_Float16)br[i].z; hb.h[3] = (_Float16)br[i].w;
      const int off = r * 64 + (((sc4 >> 1) ^ (r & 7)) << 3) + ((sc4 & 1) << 2);
      *(uint2*)&As[off] = ha.u2;
      *(uint2*)&Bs[off] = hb.u2;
    }
    __syncthreads();
    // issue next chunk's global loads early (overlap with MFMA below)
    if (kc + 1 < NKCHUNK) {
      const int kf = (kc + 1) * BK;
#pragma unroll
      for (int i = 0; i < 4; ++i) {
        ar[i] = *(const float4*)&x[(size_t)(rowBase + sr + i * 16) * D_ + kf + sc4 * 4];
        br[i] = *(const float4*)&w[(size_t)(sr + i * 16) * D_ + kf + sc4 * 4];
      }
    }
    // MFMA on current chunk
#pragma unroll
    for (int ks = 0; ks < 2; ++ks) {
      half8 af[2], bf[2];
      const int u = ks * 4 + lq;
#pragma unroll
      for (int mi = 0; mi < 2; ++mi) {
        const int row = wm + mi * 16 + l15;
        af[mi] = *(const half8*)&As[row * 64 + ((u ^ (row & 7)) << 3)];
      }
#pragma unroll
      for (int ni = 0; ni < 2; ++ni) {
        const int col = wn + ni * 16 + l15;
        bf[ni] = *(const half8*)&Bs[col * 64 + ((u ^ (col & 7)) << 3)];
      }
#pragma unroll
      for (int mi = 0; mi < 2; ++mi)
#pragma unroll
        for (int ni = 0; ni < 2; ++ni)
          acc[mi][ni] = __builtin_amdgcn_mfma_f32_16x16x32_f16(af[mi], bf[ni], acc[mi][ni], 0, 0, 0);
    }
  }

  // epilogue: clamp, log->t0, column-sum partials -> S1
  float lsum[2] = {0.f, 0.f};
#pragma unroll
  for (int mi = 0; mi < 2; ++mi) {
#pragma unroll
    for (int ni = 0; ni < 2; ++ni) {
#pragma unroll
      for (int r = 0; r < 4; ++r) {
        const float v = fmaxf(acc[mi][ni][r], 1e-6f);
        const int grow = rowBase + wm + mi * 16 + lq * 4 + r;
        const int gcol = wn + ni * 16 + l15;
        t0[(size_t)grow * E_ + gcol] = __logf(v);
        lsum[ni] += v;
      }
    }
  }
#pragma unroll
  for (int ni = 0; ni < 2; ++ni) {
    float v = lsum[ni];
    v += __shfl_xor(v, 16);
    v += __shfl_xor(v, 32);
    if (lq == 0) wsum[wv][ni * 16 + l15] = v;   // expert = wn + ni*16 + l15
  }
  __syncthreads();
  if (tid < 64) {
    const int e = tid;
    const float v = (e < 32) ? (wsum[0][e] + wsum[2][e])
                             : (wsum[1][e - 32] + wsum[3][e - 32]);
    atomicAdd(&S1[b * E_ + e], v);
  }
}

// ---------------------------------------------------------------------------
// One Sinkhorn iteration (fused col+row pass):
//   C_it[e] = log(slots[0][b][e]) + sum_{j=1..it-1} log(slots[j][b][e])
//   p = exp(t0 - C), s = row-sum(p); if last: out = p/s; else slot[it] += sum p/s
// ---------------------------------------------------------------------------
__global__ __launch_bounds__(256) void sinkhorn_iter(const float* __restrict__ t0,
                                                     float* __restrict__ slots,
                                                     float* __restrict__ out,
                                                     int it, int last) {
  const int tid = threadIdx.x;
  const int lane = tid & 63;
  const int wv = tid >> 6;
  const int b = blockIdx.x >> 8;
  const int chunk = blockIdx.x & 255;      // 256 chunks x 32 tokens per batch

  float C = __logf(slots[b * E_ + lane]);
  for (int j = 1; j < it; ++j) C += __logf(slots[j * (B_ * E_) + b * E_ + lane]);

  float colacc = 0.f;
  const int nbase = chunk * 32 + wv * 8;
#pragma unroll
  for (int i = 0; i < 8; ++i) {
    const int n = nbase + i;
    const float v = t0[((size_t)b * N_ + n) * E_ + lane];
    const float p = __expf(v - C);
    float s = p;
    s += __shfl_xor(s, 1);  s += __shfl_xor(s, 2);  s += __shfl_xor(s, 4);
    s += __shfl_xor(s, 8);  s += __shfl_xor(s, 16); s += __shfl_xor(s, 32);
    const float q = p / s;
    if (last) out[((size_t)b * N_ + n) * E_ + lane] = q;
    else      colacc += q;
  }
  if (!last) {
    __shared__ float wsum[4][64];
    wsum[wv][lane] = colacc;
    __syncthreads();
    if (tid < 64) {
      const float tot = wsum[0][tid] + wsum[1][tid] + wsum[2][tid] + wsum[3][tid];
      atomicAdd(&slots[it * (B_ * E_) + b * E_ + tid], tot);
    }
  }
}

// ---------------------------------------------------------------------------
extern "C" void kernel_launch(void* const* d_in, const int* in_sizes, int n_in,
                              void* d_out, int out_size, void* d_ws, size_t ws_size,
                              hipStream_t stream) {
  (void)in_sizes; (void)n_in; (void)out_size; (void)ws_size;
  const float* x = (const float*)d_in[0];
  const float* w = (const float*)d_in[1];
  float* out = (float*)d_out;          // t0 lives here too (same size), then
                                       // final iteration overwrites in place
  float* slots = (float*)d_ws;         // [8][B_][E_] accumulators (8 KiB)

  hipMemsetAsync(slots, 0, 8 * B_ * E_ * sizeof(float), stream);
  gemm_log<<<M_ / BM, 256, 0, stream>>>(x, w, out, slots);
  for (int it = 1; it <= 8; ++it)
    sinkhorn_iter<<<B_ * 256, 256, 0, stream>>>(out, slots, out, it, it == 8 ? 1 : 0);
}

// Round 2
// 218.391 us; speedup vs baseline: 1.0797x; 1.0797x over previous
//
#include <hip/hip_runtime.h>
#include <hip/hip_bf16.h>
#include <hip/hip_fp16.h>

#define B_ 4
#define N_ 8192
#define D_ 4096
#define E_ 64
#define M_ (B_ * N_)          // 32768 tokens
#define BM 64
#define BK 64
#define NK (D_ / BK)          // 64 K-chunks

typedef _Float16 half8 __attribute__((ext_vector_type(8)));
typedef float f32x4 __attribute__((ext_vector_type(4)));

// ---------------------------------------------------------------------------
// GEMM: gates = x @ w^T (f16 MFMA, fp32 accum), epilogue t0=log(clamp) + col sums.
// 512 threads / 8 waves, double-buffered LDS, ONE raw barrier per chunk
// (lgkmcnt(0) only — global prefetch loads stay in flight across the barrier).
// ---------------------------------------------------------------------------
__global__ __launch_bounds__(512, 4) void gemm_log(const float* __restrict__ x,
                                                   const float* __restrict__ w,
                                                   float* __restrict__ t0,
                                                   float* __restrict__ S1) {
  __shared__ _Float16 As[2][BM * BK];
  __shared__ _Float16 Bs[2][E_ * BK];
  __shared__ float wsum[8][32];

  const int tid = threadIdx.x;
  const int lane = tid & 63;
  const int wv = tid >> 6;              // 0..7
  const int wm = (wv >> 1) * 16;        // wave row base (16 rows)
  const int wn = (wv & 1) * 32;         // wave col base (32 cols)
  const int l15 = lane & 15;
  const int lq = lane >> 4;             // k-quarter
  const int rowBase = blockIdx.x * BM;
  const int b = rowBase / N_;

  // staging: thread -> (row 0..63, 16B-unit 0..7); unit swizzled by row&7
  const int sr = tid >> 3;
  const int su = tid & 7;
  const size_t xoff = (size_t)(rowBase + sr) * D_ + su * 8;
  const size_t woff = (size_t)sr * D_ + su * 8;
  const int sdst = sr * 64 + ((su ^ (sr & 7)) << 3);

  // loop-invariant fragment offsets
  const int arow = wm + l15;
  int aoff[2], boff[2][2];
#pragma unroll
  for (int ks = 0; ks < 2; ++ks)
    aoff[ks] = arow * 64 + (((ks * 4 + lq) ^ (arow & 7)) << 3);
#pragma unroll
  for (int ni = 0; ni < 2; ++ni) {
    const int bcol = wn + ni * 16 + l15;
#pragma unroll
    for (int ks = 0; ks < 2; ++ks)
      boff[ni][ks] = bcol * 64 + (((ks * 4 + lq) ^ (bcol & 7)) << 3);
  }

  f32x4 acc[2] = {};
  float4 xa, xb, wa, wb;

  // prologue: chunk-0 loads
  xa = *(const float4*)&x[xoff];     xb = *(const float4*)&x[xoff + 4];
  wa = *(const float4*)&w[woff];     wb = *(const float4*)&w[woff + 4];

  for (int kc = 0; kc < NK; ++kc) {
    const int cur = kc & 1;
    // convert chunk kc (compiler inserts the vmcnt wait here) and stage to LDS
    half8 hx, hw;
    hx[0] = (_Float16)xa.x; hx[1] = (_Float16)xa.y; hx[2] = (_Float16)xa.z; hx[3] = (_Float16)xa.w;
    hx[4] = (_Float16)xb.x; hx[5] = (_Float16)xb.y; hx[6] = (_Float16)xb.z; hx[7] = (_Float16)xb.w;
    hw[0] = (_Float16)wa.x; hw[1] = (_Float16)wa.y; hw[2] = (_Float16)wa.z; hw[3] = (_Float16)wa.w;
    hw[4] = (_Float16)wb.x; hw[5] = (_Float16)wb.y; hw[6] = (_Float16)wb.z; hw[7] = (_Float16)wb.w;
    *(half8*)&As[cur][sdst] = hx;
    *(half8*)&Bs[cur][sdst] = hw;

    // issue next chunk's global loads — they stay in flight across the barrier
    if (kc + 1 < NK) {
      const size_t o = (size_t)(kc + 1) * BK;
      xa = *(const float4*)&x[xoff + o]; xb = *(const float4*)&x[xoff + o + 4];
      wa = *(const float4*)&w[woff + o]; wb = *(const float4*)&w[woff + o + 4];
    }

    // raw barrier: drain LDS ops only, NOT vmcnt
    asm volatile("s_waitcnt lgkmcnt(0)" ::: "memory");
    __builtin_amdgcn_s_barrier();

    // fragments + MFMA
    half8 a0 = *(const half8*)&As[cur][aoff[0]];
    half8 a1 = *(const half8*)&As[cur][aoff[1]];
    half8 b00 = *(const half8*)&Bs[cur][boff[0][0]];
    half8 b01 = *(const half8*)&Bs[cur][boff[0][1]];
    half8 b10 = *(const half8*)&Bs[cur][boff[1][0]];
    half8 b11 = *(const half8*)&Bs[cur][boff[1][1]];
    acc[0] = __builtin_amdgcn_mfma_f32_16x16x32_f16(a0, b00, acc[0], 0, 0, 0);
    acc[0] = __builtin_amdgcn_mfma_f32_16x16x32_f16(a1, b01, acc[0], 0, 0, 0);
    acc[1] = __builtin_amdgcn_mfma_f32_16x16x32_f16(a0, b10, acc[1], 0, 0, 0);
    acc[1] = __builtin_amdgcn_mfma_f32_16x16x32_f16(a1, b11, acc[1], 0, 0, 0);
  }

  // epilogue: clamp, log->t0, column sums -> S1
  float lsum[2] = {0.f, 0.f};
#pragma unroll
  for (int ni = 0; ni < 2; ++ni) {
#pragma unroll
    for (int r = 0; r < 4; ++r) {
      const float v = fmaxf(acc[ni][r], 1e-6f);
      const int grow = rowBase + wm + lq * 4 + r;
      const int gcol = wn + ni * 16 + l15;
      t0[(size_t)grow * E_ + gcol] = __logf(v);
      lsum[ni] += v;
    }
  }
#pragma unroll
  for (int ni = 0; ni < 2; ++ni) {
    float v = lsum[ni];
    v += __shfl_xor(v, 16);
    v += __shfl_xor(v, 32);
    if (lq == 0) wsum[wv][ni * 16 + l15] = v;   // col = wn + ni*16 + l15
  }
  __syncthreads();
  if (tid < 64) {
    const int e = tid;
    const int half = e >> 5;      // which wn
    const int idx = e & 31;       // ni*16+l15
    const float tot = wsum[0 * 2 + half][idx] + wsum[1 * 2 + half][idx] +
                      wsum[2 * 2 + half][idx] + wsum[3 * 2 + half][idx];
    atomicAdd(&S1[b * E_ + e], tot);
  }
}

// ---------------------------------------------------------------------------
// One Sinkhorn iteration (fused col+row pass):
//   C_it[e] = sum_j log(slots[j][b][e]); p = exp(t0 - C); s = row-sum(p);
//   last: out = p/s; else slots[it] += col-sum(p/s)
// ---------------------------------------------------------------------------
__global__ __launch_bounds__(256) void sinkhorn_iter(const float* __restrict__ t0,
                                                     float* __restrict__ slots,
                                                     float* __restrict__ out,
                                                     int it, int last) {
  const int tid = threadIdx.x;
  const int lane = tid & 63;
  const int wv = tid >> 6;
  const int b = blockIdx.x >> 8;
  const int chunk = blockIdx.x & 255;

  float C = __logf(slots[b * E_ + lane]);
  for (int j = 1; j < it; ++j) C += __logf(slots[j * (B_ * E_) + b * E_ + lane]);

  float colacc = 0.f;
  const int nbase = chunk * 32 + wv * 8;
#pragma unroll
  for (int i = 0; i < 8; ++i) {
    const int n = nbase + i;
    const float v = t0[((size_t)b * N_ + n) * E_ + lane];
    const float p = __expf(v - C);
    float s = p;
    s += __shfl_xor(s, 1);  s += __shfl_xor(s, 2);  s += __shfl_xor(s, 4);
    s += __shfl_xor(s, 8);  s += __shfl_xor(s, 16); s += __shfl_xor(s, 32);
    const float q = p / s;
    if (last) out[((size_t)b * N_ + n) * E_ + lane] = q;
    else      colacc += q;
  }
  if (!last) {
    __shared__ float wsum[4][64];
    wsum[wv][lane] = colacc;
    __syncthreads();
    if (tid < 64) {
      const float tot = wsum[0][tid] + wsum[1][tid] + wsum[2][tid] + wsum[3][tid];
      atomicAdd(&slots[it * (B_ * E_) + b * E_ + tid], tot);
    }
  }
}

// ---------------------------------------------------------------------------
extern "C" void kernel_launch(void* const* d_in, const int* in_sizes, int n_in,
                              void* d_out, int out_size, void* d_ws, size_t ws_size,
                              hipStream_t stream) {
  (void)in_sizes; (void)n_in; (void)out_size; (void)ws_size;
  const float* x = (const float*)d_in[0];
  const float* w = (const float*)d_in[1];
  float* out = (float*)d_out;          // t0 lives here, final iter overwrites in place
  float* slots = (float*)d_ws;         // [8][B_][E_] accumulators

  hipMemsetAsync(slots, 0, 8 * B_ * E_ * sizeof(float), stream);
  gemm_log<<<M_ / BM, 512, 0, stream>>>(x, w, out, slots);
  for (int it = 1; it <= 8; ++it)
    sinkhorn_iter<<<B_ * 256, 256, 0, stream>>>(out, slots, out, it, it == 8 ? 1 : 0);
}